// Round 1
// baseline (402.634 us; speedup 1.0000x reference)
//
#include <hip/hip_runtime.h>
#include <hip/hip_bf16.h>
#include <math.h>

#define MAXO 16

// ---------------------------------------------------------------------------
// Kernel 1: per-batch matching + loc loss
// ---------------------------------------------------------------------------
__global__ void match_kernel(const float* __restrict__ boxes,   // [B,O,4] xy
                             const int*   __restrict__ labels,  // [B,O]
                             const float* __restrict__ dboxes,  // [D,4] cxcy
                             const float* __restrict__ locs,    // [B,D,4]
                             int*   __restrict__ tcls,          // [B,D] (temp: obj idx, then label)
                             float* __restrict__ ovlbuf,        // [B,D] (temp: overlap, later neg_loss)
                             int*   __restrict__ n_pos,         // [B]
                             double* __restrict__ loc_sum,      // [1]
                             int*   __restrict__ npt,           // [1]
                             int D, int O) {
    int b = blockIdx.x;
    int t = threadIdx.x;

    __shared__ float sbox[MAXO][4];
    __shared__ float sarea[MAXO];
    __shared__ int   slab[MAXO];
    __shared__ float rv[MAXO][256];
    __shared__ int   ri[MAXO][256];
    __shared__ double sred[256];
    __shared__ int    sredi[256];

    if (t < O) {
        const float* bp = boxes + ((size_t)b * O + t) * 4;
        float x1 = bp[0], y1 = bp[1], x2 = bp[2], y2 = bp[3];
        sbox[t][0] = x1; sbox[t][1] = y1; sbox[t][2] = x2; sbox[t][3] = y2;
        sarea[t] = (x2 - x1) * (y2 - y1);
        slab[t]  = labels[(size_t)b * O + t];
    }
    __syncthreads();

    // per-thread running argmaxes
    float bestv[MAXO];
    int   besti[MAXO];
    for (int o = 0; o < O; ++o) { bestv[o] = -1.0f; besti[o] = 0x7fffffff; }

    size_t rowoff = (size_t)b * D;

    for (int d = t; d < D; d += 256) {
        float4 db = ((const float4*)dboxes)[d];
        float dx1 = db.x - db.z * 0.5f, dy1 = db.y - db.w * 0.5f;
        float dx2 = db.x + db.z * 0.5f, dy2 = db.y + db.w * 0.5f;
        float a2 = (dx2 - dx1) * (dy2 - dy1);
        float mval = -1.0f; int mobj = 0;
        for (int o = 0; o < O; ++o) {
            float lx = fmaxf(sbox[o][0], dx1), ly = fmaxf(sbox[o][1], dy1);
            float rx = fminf(sbox[o][2], dx2), ry = fminf(sbox[o][3], dy2);
            float w = fmaxf(rx - lx, 0.0f), h = fmaxf(ry - ly, 0.0f);
            float inter = w * h;
            float iou = inter / (sarea[o] + a2 - inter);
            if (iou > mval) { mval = iou; mobj = o; }                 // first-wins over o
            if (iou > bestv[o] || (iou == bestv[o] && d < besti[o])) { // lowest-d wins
                bestv[o] = iou; besti[o] = d;
            }
        }
        tcls[rowoff + d]   = mobj;
        ovlbuf[rowoff + d] = mval;
    }

    // block-reduce per-object argmax (lowest index on ties)
    for (int o = 0; o < O; ++o) { rv[o][t] = bestv[o]; ri[o][t] = besti[o]; }
    __syncthreads();
    for (int s = 128; s > 0; s >>= 1) {
        if (t < s) {
            for (int o = 0; o < O; ++o) {
                float v2 = rv[o][t + s]; int i2 = ri[o][t + s];
                float v1 = rv[o][t];     int i1 = ri[o][t];
                if (v2 > v1 || (v2 == v1 && i2 < i1)) { rv[o][t] = v2; ri[o][t] = i2; }
            }
        }
        __syncthreads();
    }
    if (t == 0) {
        // sequential last-write-wins override (numpy scatter semantics)
        for (int o = 0; o < O; ++o) {
            int dstar = ri[o][0];
            tcls[rowoff + dstar]   = o;
            ovlbuf[rowoff + dstar] = 1.0f;
        }
    }
    __syncthreads();

    // pass 2: labels, encode, smooth-L1 for positives
    double acc = 0.0;
    int cnt = 0;
    for (int d = t; d < D; d += 256) {
        int o = tcls[rowoff + d];
        float ov = ovlbuf[rowoff + d];
        int lab = (ov < 0.5f) ? 0 : slab[o];
        tcls[rowoff + d] = lab;
        if (lab != 0) {
            cnt++;
            float x1 = sbox[o][0], y1 = sbox[o][1], x2 = sbox[o][2], y2 = sbox[o][3];
            float cx = (x1 + x2) * 0.5f, cy = (y1 + y2) * 0.5f;
            float w = x2 - x1, h = y2 - y1;
            float4 db = ((const float4*)dboxes)[d];
            float g0 = (cx - db.x) / (db.z / 10.0f);
            float g1 = (cy - db.y) / (db.w / 10.0f);
            float g2 = logf(w / db.z) * 5.0f;
            float g3 = logf(h / db.w) * 5.0f;
            const float* lp = locs + (rowoff + d) * 4;
            float dd;
            dd = fabsf(lp[0] - g0); acc += (dd < 1.0f) ? 0.5f * dd * dd : dd - 0.5f;
            dd = fabsf(lp[1] - g1); acc += (dd < 1.0f) ? 0.5f * dd * dd : dd - 0.5f;
            dd = fabsf(lp[2] - g2); acc += (dd < 1.0f) ? 0.5f * dd * dd : dd - 0.5f;
            dd = fabsf(lp[3] - g3); acc += (dd < 1.0f) ? 0.5f * dd * dd : dd - 0.5f;
        }
    }
    sred[t] = acc; sredi[t] = cnt;
    __syncthreads();
    for (int s = 128; s > 0; s >>= 1) {
        if (t < s) { sred[t] += sred[t + s]; sredi[t] += sredi[t + s]; }
        __syncthreads();
    }
    if (t == 0) {
        n_pos[b] = sredi[0];
        atomicAdd(npt, sredi[0]);
        atomicAdd(loc_sum, sred[0]);
    }
}

// ---------------------------------------------------------------------------
// Kernel 2: per-row cross-entropy (wave per row)
// ---------------------------------------------------------------------------
__global__ void ce_kernel(const float* __restrict__ cls,  // [R,C]
                          const int*   __restrict__ tcls, // [R]
                          float* __restrict__ negbuf,     // [R]
                          double* __restrict__ pos_sum,   // [1]
                          int R, int C) {
    int gid  = blockIdx.x * blockDim.x + threadIdx.x;
    int wid  = gid >> 6;
    int lane = threadIdx.x & 63;
    int nw   = (gridDim.x * blockDim.x) >> 6;

    double acc = 0.0;
    for (int r = wid; r < R; r += nw) {
        const float* base = cls + (size_t)r * C;
        int i0 = lane, i1 = lane + 64;
        float v0 = (i0 < C) ? base[i0] : -INFINITY;
        float v1 = (i1 < C) ? base[i1] : -INFINITY;
        float m = fmaxf(v0, v1);
        for (int s = 32; s > 0; s >>= 1) m = fmaxf(m, __shfl_xor(m, s));
        float e = ((i0 < C) ? expf(v0 - m) : 0.0f) + ((i1 < C) ? expf(v1 - m) : 0.0f);
        for (int s = 32; s > 0; s >>= 1) e += __shfl_xor(e, s);
        int tgt = tcls[r];
        int src = (tgt < 64) ? tgt : (tgt - 64);
        float t0 = __shfl(v0, src);
        float t1 = __shfl(v1, src);
        float lt = (tgt < 64) ? t0 : t1;
        float ce = logf(e) + m - lt;      // = -(log_softmax at target)
        if (ce < 0.0f) ce = 0.0f;          // guard rounding (keeps uint-order valid)
        if (lane == 0) {
            if (tgt != 0) { acc += (double)ce; negbuf[r] = 0.0f; }
            else          { negbuf[r] = ce; }
        }
    }
    if (lane == 0) atomicAdd(pos_sum, acc);
}

// ---------------------------------------------------------------------------
// Kernel 3: per-batch exact sum of top-k via byte radix-select on float bits
// (all values >= 0, so uint order == float order)
// ---------------------------------------------------------------------------
__global__ void hardneg_kernel(const float* __restrict__ neg,  // [B,D]
                               const int*   __restrict__ n_pos,
                               double* __restrict__ neg_sum,   // [1]
                               int D) {
    int b = blockIdx.x, t = threadIdx.x;
    const float* row = neg + (size_t)b * D;

    __shared__ unsigned int bins[256];
    __shared__ unsigned int sh_kk, sh_prefix, sh_pmask;
    __shared__ int sh_k;
    __shared__ double sred[256];

    if (t == 0) {
        int k = 3 * n_pos[b];
        if (k > D) k = D;
        sh_k = k;
        sh_kk = (unsigned)k; sh_prefix = 0u; sh_pmask = 0u;
    }
    __syncthreads();
    if (sh_k <= 0) return;

    for (int shift = 24; shift >= 0; shift -= 8) {
        bins[t] = 0;
        __syncthreads();
        unsigned pmask = sh_pmask, prefix = sh_prefix;
        for (int i = t; i < D; i += 256) {
            unsigned v = __float_as_uint(row[i]);
            if ((v & pmask) == prefix) atomicAdd(&bins[(v >> shift) & 255u], 1u);
        }
        __syncthreads();
        if (t == 0) {
            unsigned kk = sh_kk, cum = 0; int sel = 0;
            for (int bb = 255; bb >= 0; --bb) {
                unsigned c = bins[bb];
                if (cum + c >= kk) { sel = bb; break; }
                cum += c;
            }
            sh_kk = kk - cum;
            sh_prefix = prefix | ((unsigned)sel << shift);
            sh_pmask = pmask | (255u << shift);
        }
        __syncthreads();
    }
    unsigned T = sh_prefix, kk_rem = sh_kk;

    double local = 0.0;
    for (int i = t; i < D; i += 256) {
        unsigned v = __float_as_uint(row[i]);
        if (v > T) local += (double)row[i];
    }
    sred[t] = local;
    __syncthreads();
    for (int s = 128; s > 0; s >>= 1) {
        if (t < s) sred[t] += sred[t + s];
        __syncthreads();
    }
    if (t == 0) {
        double tot = sred[0] + (double)kk_rem * (double)__uint_as_float(T);
        atomicAdd(neg_sum, tot);
    }
}

// ---------------------------------------------------------------------------
// Kernel 4: finalize the two scalars
// ---------------------------------------------------------------------------
__global__ void finalize_kernel(const double* __restrict__ loc_sum,
                                const double* __restrict__ pos_sum,
                                const double* __restrict__ neg_sum,
                                const int*    __restrict__ npt,
                                float* __restrict__ out) {
    double n = (double)(*npt);
    out[0] = (float)((*loc_sum) / (n * 4.0));            // ALPHA = 1.0
    out[1] = (float)(((*neg_sum) + (*pos_sum)) / n);
}

// ---------------------------------------------------------------------------
extern "C" void kernel_launch(void* const* d_in, const int* in_sizes, int n_in,
                              void* d_out, int out_size, void* d_ws, size_t ws_size,
                              hipStream_t stream) {
    const float* locs   = (const float*)d_in[0];
    const float* cls    = (const float*)d_in[1];
    const float* boxes  = (const float*)d_in[2];
    const int*   labels = (const int*)d_in[3];
    const float* dboxes = (const float*)d_in[4];

    int D = in_sizes[4] / 4;
    int B = in_sizes[0] / (4 * D);
    int O = in_sizes[3] / B;
    int C = in_sizes[1] / (B * D);
    int R = B * D;

    char* ws = (char*)d_ws;
    double* loc_sum = (double*)ws;        // [0,8)
    double* pos_sum = loc_sum + 1;        // [8,16)
    double* neg_sum = loc_sum + 2;        // [16,24)
    int*    npt     = (int*)(ws + 24);    // [24,28)
    int*    n_pos   = (int*)(ws + 32);    // [32, 32+4B)
    size_t off = 32 + (size_t)B * 4;
    off = (off + 15) & ~(size_t)15;
    int*    tcls    = (int*)(ws + off);   off += (size_t)R * 4;
    float*  negbuf  = (float*)(ws + off);

    hipMemsetAsync(d_ws, 0, 32, stream);

    match_kernel<<<B, 256, 0, stream>>>(boxes, labels, dboxes, locs,
                                        tcls, negbuf, n_pos, loc_sum, npt, D, O);
    ce_kernel<<<2048, 256, 0, stream>>>(cls, tcls, negbuf, pos_sum, R, C);
    hardneg_kernel<<<B, 256, 0, stream>>>(negbuf, n_pos, neg_sum, D);
    finalize_kernel<<<1, 1, 0, stream>>>(loc_sum, pos_sum, neg_sum, npt, (float*)d_out);
}